// Round 1
// baseline (228.183 us; speedup 1.0000x reference)
//
#include <hip/hip_runtime.h>

// dense_image_warp: B=8, H=1024, W=768, C=3, fp32.
// query (qy,qx) = grid - flow; y0=clip(floor(qy),0,H-2); ay=clip(qy-y0,0,1);
// bilinear blend of 4 corners, per channel.

constexpr int B = 8;
constexpr int H = 1024;
constexpr int W = 768;   // 768 = 3 * 256 -> grid.x = 3 with block 256
constexpr int C = 3;

__global__ __launch_bounds__(256) void warp_kernel(
    const float* __restrict__ image,   // [B,H,W,3]
    const float* __restrict__ flow,    // [B,H,W,2]
    float* __restrict__ out)           // [B,H,W,3]
{
    const int x = blockIdx.x * 256 + threadIdx.x;
    const int y = blockIdx.y;
    const int b = blockIdx.z;

    const size_t pix = ((size_t)b * H + y) * W + x;

    // flow: coalesced float2 load. flow[...,0]=dy, flow[...,1]=dx
    const float2 f = ((const float2*)flow)[pix];
    const float qy = (float)y - f.x;
    const float qx = (float)x - f.y;

    float y0f = floorf(qy);
    float x0f = floorf(qx);
    y0f = fminf(fmaxf(y0f, 0.0f), (float)(H - 2));
    x0f = fminf(fmaxf(x0f, 0.0f), (float)(W - 2));
    const float ay = fminf(fmaxf(qy - y0f, 0.0f), 1.0f);
    const float ax = fminf(fmaxf(qx - x0f, 0.0f), 1.0f);

    const int y0 = (int)y0f;
    const int x0 = (int)x0f;

    const float* __restrict__ top = image + (((size_t)b * H + y0) * W + x0) * C;
    const float* __restrict__ bot = top + (size_t)W * C;

    float r[C];
#pragma unroll
    for (int c = 0; c < C; ++c) {
        const float tl = top[c];
        const float tr = top[c + C];
        const float bl = bot[c];
        const float br = bot[c + C];
        const float t  = tl + ax * (tr - tl);
        const float bo = bl + ax * (br - bl);
        r[c] = t + ay * (bo - t);
    }

    float* __restrict__ o = out + pix * C;
#pragma unroll
    for (int c = 0; c < C; ++c) o[c] = r[c];
}

extern "C" void kernel_launch(void* const* d_in, const int* in_sizes, int n_in,
                              void* d_out, int out_size, void* d_ws, size_t ws_size,
                              hipStream_t stream) {
    const float* image = (const float*)d_in[0];
    const float* flow  = (const float*)d_in[1];
    float* out = (float*)d_out;

    dim3 grid(W / 256, H, B);
    dim3 block(256);
    warp_kernel<<<grid, block, 0, stream>>>(image, flow, out);
}

// Round 3
// 227.020 us; speedup vs baseline: 1.0051x; 1.0051x over previous
//
#include <hip/hip_runtime.h>

// dense_image_warp: B=8, H=1024, W=768, C=3, fp32.
// R3 = R2 with compile fix: nontemporal builtins need clang ext_vector_type,
// not HIP_vector_type structs.
// XCD-locality swizzle: flat 1D grid, blockIdx % 8 = XCD (round-robin
// heuristic). Each XCD gets one batch b and walks its rows sequentially, so
// the +/-20-row gather window stays resident in that XCD's private 4 MB L2.
// Flow load + out store are non-temporal to keep cache capacity for image.

constexpr int B = 8;
constexpr int H = 1024;
constexpr int W = 768;   // 3 blocks of 256 per row
constexpr int C = 3;
constexpr int XBLKS = W / 256;            // 3
constexpr int BLOCKS_PER_XCD = (B * H * XBLKS) / 8;  // 3072 (one batch per XCD)

typedef float vfloat2 __attribute__((ext_vector_type(2)));

__global__ __launch_bounds__(256) void warp_kernel(
    const float* __restrict__ image,   // [B,H,W,3]
    const float* __restrict__ flow,    // [B,H,W,2]
    float* __restrict__ out)           // [B,H,W,3]
{
    // ---- XCD-aware decomposition ----
    const int flat = blockIdx.x;           // 0..24575
    const int xcd  = flat & 7;             // round-robin XCD hint
    const int seq  = flat >> 3;            // temporal order within XCD
    const int band = xcd * BLOCKS_PER_XCD + seq;
    const int xblk    = band % XBLKS;
    const int rowflat = band / XBLKS;      // 0..8191
    const int y = rowflat & (H - 1);
    const int b = rowflat >> 10;           // H = 1024

    const int x = xblk * 256 + threadIdx.x;
    const size_t pix = ((size_t)b * H + y) * W + x;

    // flow: coalesced 8B, read-once -> non-temporal
    const vfloat2 f =
        __builtin_nontemporal_load((const vfloat2*)flow + pix);
    const float qy = (float)y - f.x;
    const float qx = (float)x - f.y;

    float y0f = floorf(qy);
    float x0f = floorf(qx);
    y0f = fminf(fmaxf(y0f, 0.0f), (float)(H - 2));
    x0f = fminf(fmaxf(x0f, 0.0f), (float)(W - 2));
    const float ay = fminf(fmaxf(qy - y0f, 0.0f), 1.0f);
    const float ax = fminf(fmaxf(qx - x0f, 0.0f), 1.0f);

    const int y0 = (int)y0f;
    const int x0 = (int)x0f;

    const float* __restrict__ top = image + (((size_t)b * H + y0) * W + x0) * C;
    const float* __restrict__ bot = top + (size_t)W * C;

    float r[C];
#pragma unroll
    for (int c = 0; c < C; ++c) {
        const float tl = top[c];
        const float tr = top[c + C];
        const float bl = bot[c];
        const float br = bot[c + C];
        const float t  = tl + ax * (tr - tl);
        const float bo = bl + ax * (br - bl);
        r[c] = t + ay * (bo - t);
    }

    // out: write-once -> non-temporal scalar stores (L2 merges to full lines)
    float* __restrict__ o = out + pix * C;
#pragma unroll
    for (int c = 0; c < C; ++c) __builtin_nontemporal_store(r[c], &o[c]);
}

extern "C" void kernel_launch(void* const* d_in, const int* in_sizes, int n_in,
                              void* d_out, int out_size, void* d_ws, size_t ws_size,
                              hipStream_t stream) {
    const float* image = (const float*)d_in[0];
    const float* flow  = (const float*)d_in[1];
    float* out = (float*)d_out;

    dim3 grid(B * H * XBLKS);   // 24576 blocks, flat
    dim3 block(256);
    warp_kernel<<<grid, block, 0, stream>>>(image, flow, out);
}